// Round 6
// baseline (409.939 us; speedup 1.0000x reference)
//
#include <hip/hip_runtime.h>
#include <hip/hip_fp16.h>

#define D_FEAT  128
#define HBINS   16000   // bins per range, 64 KB LDS
#define SLICES  64      // edge slices

// --- hist: block (s,r) histograms keys[slice s] restricted to node range r ---
__global__ __launch_bounds__(256) void hist_kernel(const int* __restrict__ keys,
        int* __restrict__ part, int n_edges, int n_nodes, int slice_len) {
    __shared__ int bins[HBINS];
    int s = blockIdx.x % SLICES;
    int r = blockIdx.x / SLICES;
    int lo = r * HBINS;
    int nb = n_nodes - lo; if (nb > HBINS) nb = HBINS;
    for (int i = threadIdx.x; i < nb; i += 256) bins[i] = 0;
    __syncthreads();
    int beg = s * slice_len;
    int end = beg + slice_len; if (end > n_edges) end = n_edges;
    for (int i = beg + threadIdx.x; i < end; i += 256) {
        unsigned int u = (unsigned int)(keys[i] - lo);
        if (u < (unsigned int)nb) atomicAdd(&bins[u], 1);
    }
    __syncthreads();
    int* dp = part + (size_t)s * n_nodes + lo;
    for (int i = threadIdx.x; i < nb; i += 256) dp[i] = bins[i];
}

// --- merge src-partials -> norm_l = rsqrt(max(out_deg,1)) ---
__global__ void merge_norml_kernel(const int* __restrict__ part,
                                   float* __restrict__ norm_l, int n_nodes) {
    int i = blockIdx.x * 256 + threadIdx.x;
    if (i >= n_nodes) return;
    int sum = 0;
    #pragma unroll 8
    for (int s = 0; s < SLICES; s++) sum += part[(size_t)s * n_nodes + i];
    if (sum < 1) sum = 1;
    norm_l[i] = rsqrtf((float)sum);
}

// --- sum dst-partials -> deg_sum[i], plus per-1024-chunk sums for the scan ---
__global__ void sum_deg_kernel(const int* __restrict__ part, int* __restrict__ deg_sum,
                               int* __restrict__ bsums, int n_nodes) {
    __shared__ int lds[256];
    int t = threadIdx.x;
    int base = blockIdx.x * 1024;
    int tot = 0;
    for (int j = 0; j < 4; j++) {
        int i = base + j * 256 + t;
        int v = 0;
        if (i < n_nodes) {
            #pragma unroll 8
            for (int s = 0; s < SLICES; s++) v += part[(size_t)s * n_nodes + i];
            deg_sum[i] = v;
        }
        tot += v;
    }
    lds[t] = tot;
    __syncthreads();
    for (int off = 128; off > 0; off >>= 1) {
        if (t < off) lds[t] += lds[t + off];
        __syncthreads();
    }
    if (t == 0) bsums[blockIdx.x] = lds[0];
}

// --- exclusive scan of chunk sums (nb <= 256), single block ---
__global__ void scan_sums_kernel(int* __restrict__ bsums, int nb) {
    __shared__ int tmp[256];
    int t = threadIdx.x;
    int v = (t < nb) ? bsums[t] : 0;
    tmp[t] = v;
    __syncthreads();
    for (int off = 1; off < 256; off <<= 1) {
        int x = (t >= off) ? tmp[t - off] : 0;
        __syncthreads();
        tmp[t] += x;
        __syncthreads();
    }
    if (t < nb) bsums[t] = tmp[t] - v;  // exclusive
}

// --- final scan: row_ptr[i]; rebase part[s][i] -> global base of (slice s, node i) ---
__global__ void scan_rebase_kernel(const int* __restrict__ deg_sum,
                                   const int* __restrict__ bsums,
                                   int* __restrict__ row_ptr, int* __restrict__ part,
                                   int n_nodes, int n_edges) {
    __shared__ int tmp[256];
    int t = threadIdx.x;
    int base = blockIdx.x * 1024 + t * 4;
    int v0 = 0, v1 = 0, v2 = 0, v3 = 0;
    if (base + 3 < n_nodes) {
        int4 v = *(const int4*)(deg_sum + base);
        v0 = v.x; v1 = v.y; v2 = v.z; v3 = v.w;
    } else {
        if (base + 0 < n_nodes) v0 = deg_sum[base + 0];
        if (base + 1 < n_nodes) v1 = deg_sum[base + 1];
        if (base + 2 < n_nodes) v2 = deg_sum[base + 2];
    }
    int ssum = v0 + v1 + v2 + v3;
    tmp[t] = ssum;
    __syncthreads();
    for (int off = 1; off < 256; off <<= 1) {
        int x = (t >= off) ? tmp[t - off] : 0;
        __syncthreads();
        tmp[t] += x;
        __syncthreads();
    }
    int run = bsums[blockIdx.x] + tmp[t] - ssum;  // exclusive prefix at node `base`
    int vv[4] = {v0, v1, v2, v3};
    for (int j = 0; j < 4; j++) {
        int i = base + j;
        if (i < n_nodes) {
            row_ptr[i] = run;
            int cur = run;
            for (int s = 0; s < SLICES; s++) {
                size_t idx = (size_t)s * n_nodes + i;
                int c = part[idx];
                part[idx] = cur;
                cur += c;
            }
            run += vv[j];
        }
    }
    if (blockIdx.x == 0 && t == 0) row_ptr[n_nodes] = n_edges;
}

// --- fill: block (s,r) places its edges via LDS rank counters (no global atomics) ---
__global__ __launch_bounds__(256) void fill_kernel(const int* __restrict__ src,
        const int* __restrict__ dst, const int* __restrict__ part,
        int* __restrict__ src_sorted, int n_edges, int n_nodes, int slice_len) {
    __shared__ int cnt[HBINS];
    int s = blockIdx.x % SLICES;
    int r = blockIdx.x / SLICES;
    int lo = r * HBINS;
    int nb = n_nodes - lo; if (nb > HBINS) nb = HBINS;
    for (int i = threadIdx.x; i < nb; i += 256) cnt[i] = 0;
    __syncthreads();
    const int* bp = part + (size_t)s * n_nodes;
    int beg = s * slice_len;
    int end = beg + slice_len; if (end > n_edges) end = n_edges;
    for (int i = beg + threadIdx.x; i < end; i += 256) {
        int d = dst[i];
        unsigned int u = (unsigned int)(d - lo);
        if (u < (unsigned int)nb) {
            int k = atomicAdd(&cnt[u], 1);   // LDS atomic: fast
            src_sorted[bp[d] + k] = src[i];
        }
    }
}

// --- convert: feat16 = (half)(feat * norm_l[row]); 8 elems/thread ---
__global__ void convert_kernel(const float* __restrict__ feat,
                               const float* __restrict__ norm_l,
                               __half* __restrict__ feat16, int n_nodes) {
    int t = blockIdx.x * 256 + threadIdx.x;
    int total = n_nodes * (D_FEAT / 8);
    if (t >= total) return;
    float nl = norm_l[t >> 4];   // 16 threads per 128-elem row
    const float4* fp = (const float4*)feat + (size_t)t * 2;
    float4 a = fp[0], b = fp[1];
    __half2 h0 = __floats2half2_rn(a.x * nl, a.y * nl);
    __half2 h1 = __floats2half2_rn(a.z * nl, a.w * nl);
    __half2 h2 = __floats2half2_rn(b.x * nl, b.y * nl);
    __half2 h3 = __floats2half2_rn(b.z * nl, b.w * nl);
    uint4 o;
    o.x = *(unsigned int*)&h0; o.y = *(unsigned int*)&h1;
    o.z = *(unsigned int*)&h2; o.w = *(unsigned int*)&h3;
    ((uint4*)feat16)[t] = o;
}

// --- pull: CSR, 32 lanes per node, chunked coalesced edge loads + shfl broadcast ---
__global__ __launch_bounds__(256) void pull_kernel(
        const __half* __restrict__ feat16, const int* __restrict__ src_sorted,
        const int* __restrict__ row_ptr, float* __restrict__ out, int n_nodes) {
    long long gid = (long long)blockIdx.x * blockDim.x + threadIdx.x;
    int node = (int)(gid >> 5);
    int lane = (int)(gid & 31);
    if (node >= n_nodes) return;
    int beg = row_ptr[node];
    int end = row_ptr[node + 1];
    float4 acc = make_float4(0.f, 0.f, 0.f, 0.f);
    for (int k0 = beg; k0 < end; k0 += 32) {
        int kk = k0 + lane;
        int sv = (kk < end) ? src_sorted[kk] : 0;
        int cnt = end - k0; if (cnt > 32) cnt = 32;
        #pragma unroll 4
        for (int j = 0; j < cnt; j++) {
            int sj = __shfl(sv, j, 32);
            uint2 hv = ((const uint2*)(feat16 + (size_t)sj * D_FEAT))[lane];
            float2 f0 = __half22float2(*(__half2*)&hv.x);
            float2 f1 = __half22float2(*(__half2*)&hv.y);
            acc.x += f0.x; acc.y += f0.y;
            acc.z += f1.x; acc.w += f1.y;
        }
    }
    int d = end - beg; if (d < 1) d = 1;
    float nr = rsqrtf((float)d);
    acc.x *= nr; acc.y *= nr; acc.z *= nr; acc.w *= nr;
    ((float4*)(out + (size_t)node * D_FEAT))[lane] = acc;
}

static inline size_t align16(size_t x) { return (x + 15) & ~(size_t)15; }

extern "C" void kernel_launch(void* const* d_in, const int* in_sizes, int n_in,
                              void* d_out, int out_size, void* d_ws, size_t ws_size,
                              hipStream_t stream) {
    const float* feat = (const float*)d_in[0];
    const int*   src  = (const int*)d_in[1];
    const int*   dst  = (const int*)d_in[2];
    float* out = (float*)d_out;

    const int n_nodes = in_sizes[0] / D_FEAT;   // 100000
    const int n_edges = in_sizes[1];            // 1600000

    const int NR = (n_nodes + HBINS - 1) / HBINS;            // 7 ranges
    const int slice_len = (n_edges + SLICES - 1) / SLICES;   // 25000
    const int NCH = (n_nodes + 1023) / 1024;                 // 98 scan chunks

    // ws layout (all fully written before read; no memsets needed):
    // row_ptr[n+1] | norm_l[n] | deg_sum[n] | bsums[256] | src_sorted[E] |
    // union{ part[SLICES*n] ints , feat16[n*128] halfs }
    char* p = (char*)d_ws;
    int*   row_ptr    = (int*)p;    p += align16((size_t)(n_nodes + 1) * 4);
    float* norm_l     = (float*)p;  p += align16((size_t)n_nodes * 4);
    int*   deg_sum    = (int*)p;    p += align16((size_t)n_nodes * 4);
    int*   bsums      = (int*)p;    p += align16(256 * 4);
    int*   src_sorted = (int*)p;    p += align16((size_t)n_edges * 4);
    int*   part       = (int*)p;
    __half* feat16    = (__half*)p;   // overwrites part AFTER fill has consumed it

    // 1. out-degree histogram (by src) -> norm_l
    hist_kernel<<<NR * SLICES, 256, 0, stream>>>(src, part, n_edges, n_nodes, slice_len);
    merge_norml_kernel<<<(n_nodes + 255) / 256, 256, 0, stream>>>(part, norm_l, n_nodes);

    // 2. in-degree histogram (by dst), overwrites part
    hist_kernel<<<NR * SLICES, 256, 0, stream>>>(dst, part, n_edges, n_nodes, slice_len);

    // 3. scan: deg_sum -> row_ptr; rebase part[s][i] to global CSR offsets
    sum_deg_kernel<<<NCH, 256, 0, stream>>>(part, deg_sum, bsums, n_nodes);
    scan_sums_kernel<<<1, 256, 0, stream>>>(bsums, NCH);
    scan_rebase_kernel<<<NCH, 256, 0, stream>>>(deg_sum, bsums, row_ptr, part,
                                                n_nodes, n_edges);

    // 4. counting-sort fill (LDS rank counters, zero global atomics)
    fill_kernel<<<NR * SLICES, 256, 0, stream>>>(src, dst, part, src_sorted,
                                                 n_edges, n_nodes, slice_len);

    // 5. fp16 pre-scaled features (reuses part's space)
    {
        int total = n_nodes * (D_FEAT / 8);
        convert_kernel<<<(total + 255) / 256, 256, 0, stream>>>(feat, norm_l, feat16, n_nodes);
    }

    // 6. CSR pull (sequential edge reads, fused norm_r from row_ptr)
    {
        long long total = (long long)n_nodes * 32;
        pull_kernel<<<(int)((total + 255) / 256), 256, 0, stream>>>(feat16, src_sorted,
                                                                    row_ptr, out, n_nodes);
    }
}

// Round 7
// 365.385 us; speedup vs baseline: 1.1219x; 1.1219x over previous
//
#include <hip/hip_runtime.h>
#include <hip/hip_fp16.h>

#define D_FEAT  128
#define RNODES  32000   // nodes per range; packed u16 bins: 16000 words = 64 KB LDS
#define RWORDS  16000

// --- hist: block (s,r) histograms keys[slice s] for node range r into packed u16 bins.
// Safe: per-slice per-node count <= slice_len < 32768 -> no carry between halves.
__global__ __launch_bounds__(256) void hist_kernel(const int* __restrict__ keys,
        unsigned short* __restrict__ part16, int n_edges, int n_nodes,
        int slice_len, int S) {
    __shared__ unsigned int bins[RWORDS];
    int s = blockIdx.x % S;
    int r = blockIdx.x / S;
    int lo = r * RNODES;
    int nb = n_nodes - lo; if (nb > RNODES) nb = RNODES;
    int nw = (nb + 1) >> 1;
    for (int i = threadIdx.x; i < nw; i += 256) bins[i] = 0;
    __syncthreads();
    int beg = s * slice_len;
    int end = beg + slice_len; if (end > n_edges) end = n_edges;
    for (int i = beg + threadIdx.x; i < end; i += 256) {
        unsigned int u = (unsigned int)(keys[i] - lo);
        if (u < (unsigned int)nb)
            atomicAdd(&bins[u >> 1], (u & 1) ? 65536u : 1u);
    }
    __syncthreads();
    unsigned short* dp = part16 + (size_t)s * n_nodes + lo;  // 4B-aligned (lo, s*n even)
    int full = nb >> 1;
    for (int w = threadIdx.x; w < full; w += 256)
        ((unsigned int*)dp)[w] = bins[w];
    if ((nb & 1) && threadIdx.x == 0)
        dp[nb - 1] = (unsigned short)(bins[nw - 1] & 0xffffu);
}

// --- merge+sum: norm_l from src-partials; dst chunk sums for the scan. thread<->node. ---
__global__ __launch_bounds__(256) void mergesum_kernel(
        const unsigned short* __restrict__ part_src, const unsigned short* __restrict__ part_dst,
        float* __restrict__ norm_l, int* __restrict__ bsums, int n_nodes, int S) {
    __shared__ int lds[256];
    int t = threadIdx.x;
    int i = blockIdx.x * 256 + t;
    int sum_s = 0, sum_d = 0;
    if (i < n_nodes) {
        for (int s = 0; s < S; s++) {
            sum_s += part_src[(size_t)s * n_nodes + i];
            sum_d += part_dst[(size_t)s * n_nodes + i];
        }
        int d = sum_s < 1 ? 1 : sum_s;
        norm_l[i] = rsqrtf((float)d);
    }
    lds[t] = sum_d;
    __syncthreads();
    for (int off = 128; off > 0; off >>= 1) {
        if (t < off) lds[t] += lds[t + off];
        __syncthreads();
    }
    if (t == 0) bsums[blockIdx.x] = lds[0];
}

// --- exclusive scan of chunk sums (nb <= 512), single block ---
__global__ void scan_sums_kernel(int* __restrict__ bsums, int nb) {
    __shared__ int tmp[512];
    int t = threadIdx.x;
    int v = (t < nb) ? bsums[t] : 0;
    tmp[t] = v;
    __syncthreads();
    for (int off = 1; off < 512; off <<= 1) {
        int x = (t >= off) ? tmp[t - off] : 0;
        __syncthreads();
        tmp[t] += x;
        __syncthreads();
    }
    if (t < nb) bsums[t] = tmp[t] - v;  // exclusive
}

// --- rebase: row_ptr[i] + per-(slice,node) global bases bp32. thread<->node, coalesced. ---
__global__ __launch_bounds__(256) void rebase_kernel(
        const unsigned short* __restrict__ part_dst, const int* __restrict__ bsums,
        int* __restrict__ row_ptr, int* __restrict__ bp32,
        int n_nodes, int n_edges, int S) {
    __shared__ int lds[256];
    int t = threadIdx.x;
    int i = blockIdx.x * 256 + t;
    int deg = 0;
    if (i < n_nodes)
        for (int s = 0; s < S; s++) deg += part_dst[(size_t)s * n_nodes + i];
    // inclusive scan over the block
    lds[t] = deg;
    __syncthreads();
    for (int off = 1; off < 256; off <<= 1) {
        int x = (t >= off) ? lds[t - off] : 0;
        __syncthreads();
        lds[t] += x;
        __syncthreads();
    }
    int run = bsums[blockIdx.x] + lds[t] - deg;  // exclusive prefix for node i
    if (i < n_nodes) {
        row_ptr[i] = run;
        int cur = run;
        for (int s = 0; s < S; s++) {
            size_t idx = (size_t)s * n_nodes + i;
            int c = part_dst[idx];
            bp32[idx] = cur;
            cur += c;
        }
    }
    if (blockIdx.x == 0 && t == 0) row_ptr[n_nodes] = n_edges;
}

// --- fill: block (s,r) places edges via packed-u16 LDS rank counters ---
__global__ __launch_bounds__(256) void fill_kernel(const int* __restrict__ src,
        const int* __restrict__ dst, const int* __restrict__ bp32,
        int* __restrict__ src_sorted, int n_edges, int n_nodes, int slice_len, int S) {
    __shared__ unsigned int cnt[RWORDS];
    int s = blockIdx.x % S;
    int r = blockIdx.x / S;
    int lo = r * RNODES;
    int nb = n_nodes - lo; if (nb > RNODES) nb = RNODES;
    int nw = (nb + 1) >> 1;
    for (int i = threadIdx.x; i < nw; i += 256) cnt[i] = 0;
    __syncthreads();
    const int* bp = bp32 + (size_t)s * n_nodes;
    int beg = s * slice_len;
    int end = beg + slice_len; if (end > n_edges) end = n_edges;
    for (int i = beg + threadIdx.x; i < end; i += 256) {
        int d = dst[i];
        unsigned int u = (unsigned int)(d - lo);
        if (u < (unsigned int)nb) {
            unsigned int old = atomicAdd(&cnt[u >> 1], (u & 1) ? 65536u : 1u);
            int k = (u & 1) ? (int)(old >> 16) : (int)(old & 0xffffu);
            src_sorted[bp[d] + k] = src[i];
        }
    }
}

// --- convert: feat16 = (half)(feat * norm_l[row]); 8 elems/thread ---
__global__ void convert_kernel(const float* __restrict__ feat,
                               const float* __restrict__ norm_l,
                               __half* __restrict__ feat16, int n_nodes) {
    int t = blockIdx.x * 256 + threadIdx.x;
    int total = n_nodes * (D_FEAT / 8);
    if (t >= total) return;
    float nl = norm_l[t >> 4];   // 16 threads per 128-elem row
    const float4* fp = (const float4*)feat + (size_t)t * 2;
    float4 a = fp[0], b = fp[1];
    __half2 h0 = __floats2half2_rn(a.x * nl, a.y * nl);
    __half2 h1 = __floats2half2_rn(a.z * nl, a.w * nl);
    __half2 h2 = __floats2half2_rn(b.x * nl, b.y * nl);
    __half2 h3 = __floats2half2_rn(b.z * nl, b.w * nl);
    uint4 o;
    o.x = *(unsigned int*)&h0; o.y = *(unsigned int*)&h1;
    o.z = *(unsigned int*)&h2; o.w = *(unsigned int*)&h3;
    ((uint4*)feat16)[t] = o;
}

// --- pull: CSR, 32 lanes per node, chunked coalesced edge loads + shfl broadcast ---
__global__ __launch_bounds__(256) void pull_kernel(
        const __half* __restrict__ feat16, const int* __restrict__ src_sorted,
        const int* __restrict__ row_ptr, float* __restrict__ out, int n_nodes) {
    long long gid = (long long)blockIdx.x * blockDim.x + threadIdx.x;
    int node = (int)(gid >> 5);
    int lane = (int)(gid & 31);
    if (node >= n_nodes) return;
    int beg = row_ptr[node];
    int end = row_ptr[node + 1];
    float4 acc = make_float4(0.f, 0.f, 0.f, 0.f);
    for (int k0 = beg; k0 < end; k0 += 32) {
        int kk = k0 + lane;
        int sv = (kk < end) ? src_sorted[kk] : 0;
        int cnt = end - k0; if (cnt > 32) cnt = 32;
        #pragma unroll 4
        for (int j = 0; j < cnt; j++) {
            int sj = __shfl(sv, j, 32);
            uint2 hv = ((const uint2*)(feat16 + (size_t)sj * D_FEAT))[lane];
            float2 f0 = __half22float2(*(__half2*)&hv.x);
            float2 f1 = __half22float2(*(__half2*)&hv.y);
            acc.x += f0.x; acc.y += f0.y;
            acc.z += f1.x; acc.w += f1.y;
        }
    }
    int d = end - beg; if (d < 1) d = 1;
    float nr = rsqrtf((float)d);
    acc.x *= nr; acc.y *= nr; acc.z *= nr; acc.w *= nr;
    ((float4*)(out + (size_t)node * D_FEAT))[lane] = acc;
}

static inline size_t align16(size_t x) { return (x + 15) & ~(size_t)15; }

extern "C" void kernel_launch(void* const* d_in, const int* in_sizes, int n_in,
                              void* d_out, int out_size, void* d_ws, size_t ws_size,
                              hipStream_t stream) {
    const float* feat = (const float*)d_in[0];
    const int*   src  = (const int*)d_in[1];
    const int*   dst  = (const int*)d_in[2];
    float* out = (float*)d_out;

    const int n_nodes = in_sizes[0] / D_FEAT;   // 100000
    const int n_edges = in_sizes[1];            // 1600000

    const int NR  = (n_nodes + RNODES - 1) / RNODES;   // 4 ranges
    const int NCH = (n_nodes + 255) / 256;             // 391 scan chunks (<=512)

    // fixed ws: row_ptr[n+1] | norm_l[n] | bsums[512] | src_sorted[E]
    size_t fixed = align16((size_t)(n_nodes + 1) * 4) + align16((size_t)n_nodes * 4)
                 + align16(512 * 4) + align16((size_t)n_edges * 4);
    size_t f16sz = (size_t)n_nodes * D_FEAT * 2;   // 25.6 MB

    // variable region: part_src u16[S*n] | part_dst u16[S*n] | bp32[S*n] = S*n*8 bytes,
    // later overlaid by feat16. Pick S=64 if it fits, else S=32 (region 25.6 MB == f16sz).
    int S = 64;
    size_t region = (size_t)S * n_nodes * 8;
    if (region < f16sz) region = f16sz;
    if (ws_size < fixed + region) {
        S = 32;
        region = (size_t)S * n_nodes * 8;
        if (region < f16sz) region = f16sz;
    }
    const int slice_len = (n_edges + S - 1) / S;

    char* p = (char*)d_ws;
    int*   row_ptr    = (int*)p;    p += align16((size_t)(n_nodes + 1) * 4);
    float* norm_l     = (float*)p;  p += align16((size_t)n_nodes * 4);
    int*   bsums      = (int*)p;    p += align16(512 * 4);
    int*   src_sorted = (int*)p;    p += align16((size_t)n_edges * 4);
    unsigned short* part_src = (unsigned short*)p;
    unsigned short* part_dst = part_src + (size_t)S * n_nodes;
    int*   bp32       = (int*)(part_dst + (size_t)S * n_nodes);
    __half* feat16    = (__half*)part_src;   // overlays parts+bp AFTER fill consumed them

    // 1. histograms (packed u16 LDS bins, no global atomics)
    hist_kernel<<<NR * S, 256, 0, stream>>>(src, part_src, n_edges, n_nodes, slice_len, S);
    hist_kernel<<<NR * S, 256, 0, stream>>>(dst, part_dst, n_edges, n_nodes, slice_len, S);

    // 2. norm_l + dst chunk sums -> exclusive scan -> per-(slice,node) bases + row_ptr
    mergesum_kernel<<<NCH, 256, 0, stream>>>(part_src, part_dst, norm_l, bsums, n_nodes, S);
    scan_sums_kernel<<<1, 512, 0, stream>>>(bsums, NCH);
    rebase_kernel<<<NCH, 256, 0, stream>>>(part_dst, bsums, row_ptr, bp32,
                                           n_nodes, n_edges, S);

    // 3. counting-sort fill (packed-u16 LDS rank counters)
    fill_kernel<<<NR * S, 256, 0, stream>>>(src, dst, bp32, src_sorted,
                                            n_edges, n_nodes, slice_len, S);

    // 4. fp16 pre-scaled features (overlays part/bp region)
    {
        int total = n_nodes * (D_FEAT / 8);
        convert_kernel<<<(total + 255) / 256, 256, 0, stream>>>(feat, norm_l, feat16, n_nodes);
    }

    // 5. CSR pull (fused norm_r from row_ptr)
    {
        long long total = (long long)n_nodes * 32;
        pull_kernel<<<(int)((total + 255) / 256), 256, 0, stream>>>(feat16, src_sorted,
                                                                    row_ptr, out, n_nodes);
    }
}